// Round 6
// baseline (114.797 us; speedup 1.0000x reference)
//
#include <hip/hip_runtime.h>
#include <stdint.h>

#define NDIM 8192
#define DDIM 256
#define CAP  256    // candidate capacity — keeps LDS ~2.6 KB
#define MAXK 64

typedef float v4f __attribute__((ext_vector_type(4)));

// Map float bits to an unsigned key with the same total order.
__device__ inline uint32_t f2key(float f) {
    uint32_t u = __float_as_uint(f);
    return (u & 0x80000000u) ? ~u : (u | 0x80000000u);
}

__global__ __launch_bounds__(256, 6) void topk_agg_kernel(
    const float* __restrict__ A, const float* __restrict__ X,
    const float* __restrict__ alpha_p, const int* __restrict__ k_p,
    float* __restrict__ out)
{
    const int row  = blockIdx.x;
    const int tid  = threadIdx.x;
    const int lane = tid & 63;
    const int wid  = tid >> 6;

    __shared__ unsigned long long cand[CAP];
    __shared__ int s_count;
    __shared__ int s_sel[MAXK];
    __shared__ unsigned long long s_red[4];

    int k = *k_p;
    if (k > MAXK) k = MAXK;           // defensive clamp (k==32 here)
    const float alpha = *alpha_p;

    const float* __restrict__ rowp = A + (size_t)row * NDIM;
    const v4f*   __restrict__ p    = reinterpret_cast<const v4f*>(rowp);

    // Prefetch the residual X value early (independent of selection).
    const float xres = X[(size_t)row * DDIM + tid];

    // ---- Phase 1: streaming threshold scan ----------------------------
    // No register-resident row: compare float4s as they arrive. Retries
    // (P ~ 2e-4 per row) re-read from global — negligible in aggregate.
    // thr=2.45: count ~ Bin(8192, 0.00714): E=58, sigma=7.6.
    const float thrs[6] = {2.45f, 2.0f, 3.2f, 1.2f, 0.0f, -2.0f};
    bool ok = false;
    int count = 0;

    for (int ti = 0; ti < 6 && !ok; ++ti) {
        const float thr = thrs[ti];
        if (tid == 0) s_count = 0;
        __syncthreads();

        #pragma unroll
        for (int i = 0; i < 8; ++i) {
            const v4f v = __builtin_nontemporal_load(p + i * 256 + tid);
            const int base = (i * 256 + tid) * 4;
            #pragma unroll
            for (int c = 0; c < 4; ++c) {
                const float f = v[c];
                if (f > thr) {
                    const int pos = atomicAdd(&s_count, 1);
                    if (pos < CAP) {
                        const int idx = base + c;
                        cand[pos] = ((unsigned long long)f2key(f) << 32) |
                                    (uint32_t)(~(uint32_t)idx);
                    }
                }
            }
        }
        __syncthreads();
        count = s_count;               // uniform across block
        ok = (count >= k && count <= CAP);
        __syncthreads();               // protect s_count reset next iter
    }

    // ---- Phase 2: rank-based top-k selection (no sort) ----------------
    if (ok) {
        // rank(i) = #{j : key_j > key_i}; keys unique -> ranks unique ->
        // s_sel writes race-free + deterministic. 8x unroll keeps 8
        // independent LDS broadcast reads in flight.
        if (tid < count) {
            const unsigned long long mykey = cand[tid];
            int rank = 0;
            int j = 0;
            for (; j + 8 <= count; j += 8) {
                const unsigned long long c0 = cand[j + 0];
                const unsigned long long c1 = cand[j + 1];
                const unsigned long long c2 = cand[j + 2];
                const unsigned long long c3 = cand[j + 3];
                const unsigned long long c4 = cand[j + 4];
                const unsigned long long c5 = cand[j + 5];
                const unsigned long long c6 = cand[j + 6];
                const unsigned long long c7 = cand[j + 7];
                rank += (c0 > mykey) + (c1 > mykey) + (c2 > mykey) +
                        (c3 > mykey) + (c4 > mykey) + (c5 > mykey) +
                        (c6 > mykey) + (c7 > mykey);
            }
            for (; j < count; ++j)
                rank += (cand[j] > mykey) ? 1 : 0;
            if (rank < k)
                s_sel[rank] = (int)(~(uint32_t)(mykey & 0xFFFFFFFFull));
        }
        __syncthreads();
    } else {
        // exact (slow) fallback — never triggers for normal data
        for (int t = 0; t < k; ++t) {
            unsigned long long best = 0ull;
            for (int it = 0; it < NDIM / 256; ++it) {
                const int idx = it * 256 + tid;
                const float f = rowp[idx];
                bool taken = false;
                for (int s = 0; s < t; ++s) taken |= (s_sel[s] == idx);
                if (!taken) {
                    const unsigned long long comp =
                        ((unsigned long long)f2key(f) << 32) |
                        (uint32_t)(~(uint32_t)idx);
                    if (comp > best) best = comp;
                }
            }
            #pragma unroll
            for (int o = 32; o > 0; o >>= 1) {
                const unsigned long long other = __shfl_down(best, o, 64);
                if (other > best) best = other;
            }
            if (lane == 0) s_red[wid] = best;
            __syncthreads();
            if (tid == 0) {
                unsigned long long b = s_red[0];
                for (int w = 1; w < 4; ++w)
                    if (s_red[w] > b) b = s_red[w];
                s_sel[t] = (int)(~(uint32_t)(b & 0xFFFFFFFFull));
            }
            __syncthreads();
        }
    }

    // ---- Phase 3: gather + residual -----------------------------------
    // tid == column d; per-wave reads of X row segments are 256B contiguous
    // -> coalesced, L2-resident (X = 8 MB fits each XCD's 4MB L2 working
    // slice + L3). 8 accumulators -> dependent chain is ~4 L2 latencies.
    float acc;
    if (k == 32) {
        int sel[32];
        #pragma unroll
        for (int t = 0; t < 32; ++t) sel[t] = s_sel[t];   // LDS broadcast, hoisted
        float a[8];
        #pragma unroll
        for (int q = 0; q < 8; ++q) a[q] = 0.f;
        #pragma unroll
        for (int t = 0; t < 32; ++t)
            a[t & 7] += X[(size_t)sel[t] * DDIM + tid];
        acc = ((a[0] + a[1]) + (a[2] + a[3])) + ((a[4] + a[5]) + (a[6] + a[7]));
    } else {
        acc = 0.f;
        for (int t = 0; t < k; ++t)
            acc += X[(size_t)s_sel[t] * DDIM + tid];
    }
    __builtin_nontemporal_store(xres + alpha * acc,
                                out + (size_t)row * DDIM + tid);
}

extern "C" void kernel_launch(void* const* d_in, const int* in_sizes, int n_in,
                              void* d_out, int out_size, void* d_ws, size_t ws_size,
                              hipStream_t stream) {
    const float* A     = (const float*)d_in[0];
    const float* X     = (const float*)d_in[1];
    const float* alpha = (const float*)d_in[2];
    const int*   k     = (const int*)d_in[3];
    float* out = (float*)d_out;

    topk_agg_kernel<<<NDIM, 256, 0, stream>>>(A, X, alpha, k, out);
}